// Round 4
// baseline (371.289 us; speedup 1.0000x reference)
//
#include <hip/hip_runtime.h>
#include <hip/hip_bf16.h>

// ---------------------------------------------------------------------------
// GIN multi-task forward on MI355X.
// R21: chunk-phased gather. R19/R20 both plateau at ~2.0 TB/s random-fetch
// -> bound by (miss slots x latency); only levers are L2 hit rate / latency.
// csr is src-chunk-sorted but gangs free-run, so the live src window drifts
// to ~3 chunks (~3MB > XCD L2 share); measured hit rate only 67%
// (FETCH 133.8MB vs 410MB row traffic). Fix: csr_fused exports per-
// (node,chunk) starts (rcs, 3.2MB); phase G becomes 8 synchronized
// chunk-pair phases (window 1.6MB), each thread handling both its rows;
// tails via clamped 4-wide loads (no serial scalar tail, reverts R20's
// regression). Accumulation order unchanged -> bit-identical output.
// ---------------------------------------------------------------------------

#define IN_DIM 128
#define NFINE 128        // fine dst buckets (16 per XCD)
#define BIN_EPB 4096     // edges per bin block (16/thread)
#define SRCCH 16         // src chunks per dst row (sorted order)
#define NSLOT 6400       // >= 391 * SRCCH
#define SPT 13           // scan slots per thread (512*13 >= 6400)

typedef float  f32x4  __attribute__((ext_vector_type(4)));
typedef short  bf16x4 __attribute__((ext_vector_type(4)));
typedef short  bf16x8 __attribute__((ext_vector_type(8)));

__device__ __forceinline__ unsigned short bf16_rne(float v) {
    unsigned u = __float_as_uint(v);
    unsigned t = u + 0x7fffu + ((u >> 16) & 1u);
    return (unsigned short)(t >> 16);
}

// ---------------- fp32 -> bf16 convert (RNE), 8 elems/thread ---------------

__global__ __launch_bounds__(256) void f32_to_bf16_kernel(
    const float4* __restrict__ in, uint4* __restrict__ out, int n8)
{
    int i = blockIdx.x * 256 + threadIdx.x;
    if (i >= n8) return;
    float4 a = in[i * 2];
    float4 b = in[i * 2 + 1];
    float v[8] = {a.x, a.y, a.z, a.w, b.x, b.y, b.z, b.w};
    unsigned r[4];
#pragma unroll
    for (int j = 0; j < 4; ++j)
        r[j] = (unsigned)bf16_rne(v[j * 2]) | ((unsigned)bf16_rne(v[j * 2 + 1]) << 16);
    out[i] = make_uint4(r[0], r[1], r[2], r[3]);
}

// ---------------- weight convert: W[k][n] fp32 -> Wt_h/Wt_l[n][k] bf16 -----

__global__ __launch_bounds__(256) void conv_weights_kernel(
    const float* __restrict__ W0, const float* __restrict__ W1,
    const float* __restrict__ W2, const float* __restrict__ W3,
    unsigned short* __restrict__ Wh, unsigned short* __restrict__ Wl)
{
    int m   = blockIdx.x >> 6;
    int idx = (blockIdx.x & 63) * 256 + threadIdx.x;
    const float* W = (m == 0) ? W0 : (m == 1) ? W1 : (m == 2) ? W2 : W3;
    int k = idx >> 7, n = idx & 127;
    float v = W[idx];
    unsigned short hh = bf16_rne(v);
    float hf = __uint_as_float(((unsigned)hh) << 16);
    unsigned short ll = bf16_rne(v - hf);
    Wh[m * 16384 + n * 128 + k] = hh;
    Wl[m * 16384 + n * 128 + k] = ll;
}

// ---------------- CSR build: 128-way bin -> fused hist/scan/fill -----------

__global__ __launch_bounds__(256) void bin_kernel(
    const int* __restrict__ src, const int* __restrict__ dst,
    int2* __restrict__ buckets, int* __restrict__ bcur,
    int n_edges, int n_nodes, int cap)
{
    __shared__ int cnt[NFINE];
    __shared__ int base[NFINE];
    for (int i = threadIdx.x; i < NFINE; i += 256) cnt[i] = 0;
    __syncthreads();

    const int e0 = blockIdx.x * BIN_EPB + threadIdx.x * 16;
    int ne = n_edges - e0;
    if (ne < 0) ne = 0;
    if (ne > 16) ne = 16;

    int d[16], s[16], off[16];
    if (ne == 16) {
#pragma unroll
        for (int q = 0; q < 4; ++q) {
            int4 dv = *(const int4*)(dst + e0 + q * 4);
            int4 sv = *(const int4*)(src + e0 + q * 4);
            d[q * 4 + 0] = dv.x; d[q * 4 + 1] = dv.y;
            d[q * 4 + 2] = dv.z; d[q * 4 + 3] = dv.w;
            s[q * 4 + 0] = sv.x; s[q * 4 + 1] = sv.y;
            s[q * 4 + 2] = sv.z; s[q * 4 + 3] = sv.w;
        }
    } else {
#pragma unroll
        for (int j = 0; j < 16; ++j) {
            d[j] = (j < ne) ? dst[e0 + j] : 0;
            s[j] = (j < ne) ? src[e0 + j] : 0;
        }
    }
#pragma unroll
    for (int j = 0; j < 16; ++j)
        if (j < ne) {
            int b = (int)(((long long)d[j] * NFINE) / n_nodes);
            off[j] = atomicAdd(&cnt[b], 1);
        }
    __syncthreads();
    for (int i = threadIdx.x; i < NFINE; i += 256)
        base[i] = atomicAdd(&bcur[i], cnt[i]);
    __syncthreads();
#pragma unroll
    for (int j = 0; j < 16; ++j)
        if (j < ne) {
            int b = (int)(((long long)d[j] * NFINE) / n_nodes);
            buckets[(size_t)b * cap + base[b] + off[j]] = make_int2(d[j], s[j]);
        }
}

// One block per fine bucket. Per-(node, src-chunk16) LDS histogram, blocked
// exclusive scan (13 slots/thread), row_start + per-(node,chunk) starts
// (rcs) write, LDS-cursor fill -> csr rows stored sorted by src chunk.
__global__ __launch_bounds__(512) void csr_fused_kernel(
    const int2* __restrict__ buckets, const int* __restrict__ bcnt,
    int* __restrict__ row_start, int* __restrict__ rcs,
    int* __restrict__ csr_src,
    int cap, int n_nodes, int n_edges)
{
    __shared__ int bc[NFINE];
    __shared__ int h[NSLOT];
    __shared__ int tsum[512];
    __shared__ int bbase_s;

    const int b = blockIdx.x;
    const int t = threadIdx.x;
    const int lo_n = (int)(((long long)b * n_nodes + NFINE - 1) / NFINE);
    const int hi_n = (int)(((long long)(b + 1) * n_nodes + NFINE - 1) / NFINE);
    const int sl = hi_n - lo_n;

    if (t < NFINE) bc[t] = bcnt[t];
    for (int i = t; i < NSLOT; i += 512) h[i] = 0;
    __syncthreads();
    if (t == 0) {
        int s = 0;
        for (int i = 0; i < b; ++i) s += bc[i];
        bbase_s = s;
    }
    const int nb = bc[b];
    const int2* bp = buckets + (size_t)b * cap;
    __syncthreads();

    // pass 1: per-(node, src-chunk) histogram
    for (int i = t; i < nb; i += 512) {
        int2 e = bp[i];
        int key = (e.x - lo_n) * SRCCH + (int)(((long long)e.y * SRCCH) / n_nodes);
        atomicAdd(&h[key], 1);
    }
    __syncthreads();

    // blocked exclusive scan over NSLOT entries (SPT per thread)
    int base = 0;
#pragma unroll
    for (int j = 0; j < SPT; ++j) {
        int slot = t * SPT + j;
        if (slot < NSLOT) {
            int v = h[slot];
            h[slot] = base;
            base += v;
        }
    }
    tsum[t] = base;
    __syncthreads();
    for (int off = 1; off < 512; off <<= 1) {
        int tmp = (t >= off) ? tsum[t - off] : 0;
        __syncthreads();
        tsum[t] += tmp;
        __syncthreads();
    }
    int texcl = tsum[t] - base + bbase_s;
#pragma unroll
    for (int j = 0; j < SPT; ++j) {
        int slot = t * SPT + j;
        if (slot < NSLOT) h[slot] += texcl;
    }
    __syncthreads();
    for (int i = t; i < sl; i += 512) row_start[lo_n + i] = h[i * SRCCH];
    for (int i = t; i < sl * SRCCH; i += 512) rcs[lo_n * SRCCH + i] = h[i];
    if (b == NFINE - 1 && t == 0) row_start[n_nodes] = n_edges;
    __syncthreads();

    // pass 2: fill with LDS cursors (exclusive csr window, full-line writes)
    for (int i = t; i < nb; i += 512) {
        int2 e = bp[i];
        int key = (e.x - lo_n) * SRCCH + (int)(((long long)e.y * SRCCH) / n_nodes);
        csr_src[atomicAdd(&h[key], 1)] = e.y;
    }
}

// ---------------- fused layer: gather + relu(relu(A@Wa+ba)@Wb+bb) ----------
// Block = 512 thr (8 waves) = 64 nodes. Phase G: 8 synchronized chunk-pair
// phases; each 16-lane gang handles rows gr and gr+32, processing only the
// edges whose src lies in the phase's 1.6MB slice, then __syncthreads.
// Tails use clamped 4-wide loads (loads always parallel). Split-bf16 A
// planes to LDS; phases 1/2 + epilogues unchanged from R19.
#define HSTRIDE 132

__device__ __forceinline__ void add_row8(float acc[8], uint4 r) {
    union { unsigned u; float f; } c;
    c.u = r.x << 16;         acc[0] += c.f;
    c.u = r.x & 0xffff0000u; acc[1] += c.f;
    c.u = r.y << 16;         acc[2] += c.f;
    c.u = r.y & 0xffff0000u; acc[3] += c.f;
    c.u = r.z << 16;         acc[4] += c.f;
    c.u = r.z & 0xffff0000u; acc[5] += c.f;
    c.u = r.w << 16;         acc[6] += c.f;
    c.u = r.w & 0xffff0000u; acc[7] += c.f;
}

// clamped 4-wide range gather: loads always issue in parallel, adds masked
__device__ __forceinline__ void gather_range(
    const int* __restrict__ csr_src, const uint4* __restrict__ nbr,
    int lane, int s, int e, float acc[8])
{
    for (int i = s; i < e; i += 4) {
        int i1 = (i + 1 < e) ? i + 1 : e - 1;
        int i2 = (i + 2 < e) ? i + 2 : e - 1;
        int i3 = (i + 3 < e) ? i + 3 : e - 1;
        int s0 = csr_src[i];
        int s1 = csr_src[i1];
        int s2 = csr_src[i2];
        int s3 = csr_src[i3];
        uint4 r0 = nbr[(size_t)s0 * 16 + lane];
        uint4 r1 = nbr[(size_t)s1 * 16 + lane];
        uint4 r2 = nbr[(size_t)s2 * 16 + lane];
        uint4 r3 = nbr[(size_t)s3 * 16 + lane];
        add_row8(acc, r0);
        if (i + 1 < e) add_row8(acc, r1);
        if (i + 2 < e) add_row8(acc, r2);
        if (i + 3 < e) add_row8(acc, r3);
    }
}

template <int LAYER>
__global__ __launch_bounds__(512) void fused_gin_layer_kernel(
    const float* __restrict__ xf,        // layer-1 self rows (fp32)
    const uint4* __restrict__ selfh,     // layer-2 self high plane
    const uint4* __restrict__ selfl,     // layer-2 self low plane
    const uint4* __restrict__ nbr,       // neighbor bf16 rows, 16 uint4/row
    const int* __restrict__ row_start, const int* __restrict__ rcs,
    const int* __restrict__ csr_src,
    const unsigned short* __restrict__ Wa_h, const unsigned short* __restrict__ Wa_l,
    const float* __restrict__ ba,
    const unsigned short* __restrict__ Wb_h, const unsigned short* __restrict__ Wb_l,
    const float* __restrict__ bb,
    float* __restrict__ C, unsigned short* __restrict__ Ch,
    unsigned short* __restrict__ Cl, int M)
{
    __shared__ __align__(16) unsigned short Hh[64][HSTRIDE];
    __shared__ __align__(16) unsigned short Hl[64][HSTRIDE];

    const int t    = threadIdx.x;
    const int brow = blockIdx.x * 64;

    // ---- phase G: chunk-phased gather ----
    {
        const int lane  = t & 15;        // k-slice: elems [lane*8, lane*8+8)
        const int gr    = t >> 4;        // 0..31
        const int node0 = brow + gr;
        const int node1 = brow + 32 + gr;
        const bool val0 = node0 < M;
        const bool val1 = node1 < M;

        float acc0[8] = {0.f, 0.f, 0.f, 0.f, 0.f, 0.f, 0.f, 0.f};
        float acc1[8] = {0.f, 0.f, 0.f, 0.f, 0.f, 0.f, 0.f, 0.f};
        if (val0) {
            if constexpr (LAYER == 1) {
                const f32x4* p = (const f32x4*)(xf + (size_t)node0 * IN_DIM + lane * 8);
                f32x4 a0 = p[0], a1 = p[1];
                acc0[0] = a0.x; acc0[1] = a0.y; acc0[2] = a0.z; acc0[3] = a0.w;
                acc0[4] = a1.x; acc0[5] = a1.y; acc0[6] = a1.z; acc0[7] = a1.w;
            } else {
                add_row8(acc0, selfh[(size_t)node0 * 16 + lane]);
                add_row8(acc0, selfl[(size_t)node0 * 16 + lane]);
            }
        }
        if (val1) {
            if constexpr (LAYER == 1) {
                const f32x4* p = (const f32x4*)(xf + (size_t)node1 * IN_DIM + lane * 8);
                f32x4 a0 = p[0], a1 = p[1];
                acc1[0] = a0.x; acc1[1] = a0.y; acc1[2] = a0.z; acc1[3] = a0.w;
                acc1[4] = a1.x; acc1[5] = a1.y; acc1[6] = a1.z; acc1[7] = a1.w;
            } else {
                add_row8(acc1, selfh[(size_t)node1 * 16 + lane]);
                add_row8(acc1, selfl[(size_t)node1 * 16 + lane]);
            }
        }

        const int end0 = val0 ? row_start[node0 + 1] : 0;
        const int end1 = val1 ? row_start[node1 + 1] : 0;
        int cur0 = val0 ? rcs[node0 * SRCCH] : 0;
        int cur1 = val1 ? rcs[node1 * SRCCH] : 0;

#pragma unroll 1
        for (int cp = 0; cp < 8; ++cp) {
            int e0 = 0, e1 = 0;
            if (val0) e0 = (cp < 7) ? rcs[node0 * SRCCH + cp * 2 + 2] : end0;
            if (val1) e1 = (cp < 7) ? rcs[node1 * SRCCH + cp * 2 + 2] : end1;
            gather_range(csr_src, nbr, lane, cur0, e0, acc0);
            gather_range(csr_src, nbr, lane, cur1, e1, acc1);
            cur0 = e0;
            cur1 = e1;
            __syncthreads();             // bound the block's src window
        }

        unsigned short hh[8], ll[8];
#pragma unroll
        for (int j = 0; j < 8; ++j) {
            unsigned short h = bf16_rne(acc0[j]);
            hh[j] = h;
            ll[j] = bf16_rne(acc0[j] - __uint_as_float(((unsigned)h) << 16));
        }
        *(bf16x4*)&Hh[gr][lane * 8]     = *(const bf16x4*)&hh[0];
        *(bf16x4*)&Hh[gr][lane * 8 + 4] = *(const bf16x4*)&hh[4];
        *(bf16x4*)&Hl[gr][lane * 8]     = *(const bf16x4*)&ll[0];
        *(bf16x4*)&Hl[gr][lane * 8 + 4] = *(const bf16x4*)&ll[4];
#pragma unroll
        for (int j = 0; j < 8; ++j) {
            unsigned short h = bf16_rne(acc1[j]);
            hh[j] = h;
            ll[j] = bf16_rne(acc1[j] - __uint_as_float(((unsigned)h) << 16));
        }
        *(bf16x4*)&Hh[gr + 32][lane * 8]     = *(const bf16x4*)&hh[0];
        *(bf16x4*)&Hh[gr + 32][lane * 8 + 4] = *(const bf16x4*)&hh[4];
        *(bf16x4*)&Hl[gr + 32][lane * 8]     = *(const bf16x4*)&ll[0];
        *(bf16x4*)&Hl[gr + 32][lane * 8 + 4] = *(const bf16x4*)&ll[4];
    }
    __syncthreads();

    // ---- MLP thread decomposition: wave owns 32x32 quadrant ----
    const int wave = t >> 6;
    const int lane = t & 63;
    const int l15  = lane & 15;
    const int quad = lane >> 4;
    const int rh   = (wave & 1) * 32;        // row half within block
    const int cq   = (wave >> 1) * 32;       // col quarter

    f32x4 acc[2][2];
#pragma unroll
    for (int ti = 0; ti < 2; ++ti)
#pragma unroll
        for (int ct = 0; ct < 2; ++ct) acc[ti][ct] = {0.f, 0.f, 0.f, 0.f};

    // ---- phase 1: A (LDS, split bf16) @ Wa ----
#pragma unroll
    for (int k0 = 0; k0 < IN_DIM; k0 += 32) {
        const int hk = k0 + quad * 8;
        bf16x8 ah[2], al[2];
#pragma unroll
        for (int ti = 0; ti < 2; ++ti) {
            const int hr = rh + ti * 16 + l15;
            bf16x4 h0 = *(const bf16x4*)&Hh[hr][hk];
            bf16x4 h1 = *(const bf16x4*)&Hh[hr][hk + 4];
            bf16x4 l0 = *(const bf16x4*)&Hl[hr][hk];
            bf16x4 l1 = *(const bf16x4*)&Hl[hr][hk + 4];
            ah[ti] = __builtin_shufflevector(h0, h1, 0, 1, 2, 3, 4, 5, 6, 7);
            al[ti] = __builtin_shufflevector(l0, l1, 0, 1, 2, 3, 4, 5, 6, 7);
        }
#pragma unroll
        for (int ct = 0; ct < 2; ++ct) {
            const size_t woff = (size_t)(cq + ct * 16 + l15) * IN_DIM + k0 + quad * 8;
            bf16x8 wh = *(const bf16x8*)(Wa_h + woff);
            bf16x8 wl = *(const bf16x8*)(Wa_l + woff);
            acc[0][ct] = __builtin_amdgcn_mfma_f32_16x16x32_bf16(ah[0], wh, acc[0][ct], 0, 0, 0);
            acc[1][ct] = __builtin_amdgcn_mfma_f32_16x16x32_bf16(ah[1], wh, acc[1][ct], 0, 0, 0);
            acc[0][ct] = __builtin_amdgcn_mfma_f32_16x16x32_bf16(al[0], wh, acc[0][ct], 0, 0, 0);
            acc[1][ct] = __builtin_amdgcn_mfma_f32_16x16x32_bf16(al[1], wh, acc[1][ct], 0, 0, 0);
            acc[0][ct] = __builtin_amdgcn_mfma_f32_16x16x32_bf16(ah[0], wl, acc[0][ct], 0, 0, 0);
            acc[1][ct] = __builtin_amdgcn_mfma_f32_16x16x32_bf16(ah[1], wl, acc[1][ct], 0, 0, 0);
        }
    }
    __syncthreads();   // all stage-1 LDS reads done before H overwrite

    // ---- epilogue 1: h = relu(acc + ba) -> LDS (overwrite A planes) ----
#pragma unroll
    for (int ti = 0; ti < 2; ++ti) {
#pragma unroll
        for (int ct = 0; ct < 2; ++ct) {
            int col = cq + ct * 16 + l15;
            float b = ba[col];
#pragma unroll
            for (int r = 0; r < 4; ++r) {
                int rl = rh + ti * 16 + quad * 4 + r;
                float v = fmaxf(acc[ti][ct][r] + b, 0.f);
                unsigned short hh = bf16_rne(v);
                Hh[rl][col] = hh;
                Hl[rl][col] = bf16_rne(v - __uint_as_float(((unsigned)hh) << 16));
            }
            acc[ti][ct] = {0.f, 0.f, 0.f, 0.f};
        }
    }
    __syncthreads();

    // ---- phase 2: h (LDS, split bf16) @ Wb ----
#pragma unroll
    for (int k0 = 0; k0 < IN_DIM; k0 += 32) {
        const int hk = k0 + quad * 8;
        bf16x8 ah[2], al[2];
#pragma unroll
        for (int ti = 0; ti < 2; ++ti) {
            const int hr = rh + ti * 16 + l15;
            bf16x4 h0 = *(const bf16x4*)&Hh[hr][hk];
            bf16x4 h1 = *(const bf16x4*)&Hh[hr][hk + 4];
            bf16x4 l0 = *(const bf16x4*)&Hl[hr][hk];
            bf16x4 l1 = *(const bf16x4*)&Hl[hr][hk + 4];
            ah[ti] = __builtin_shufflevector(h0, h1, 0, 1, 2, 3, 4, 5, 6, 7);
            al[ti] = __builtin_shufflevector(l0, l1, 0, 1, 2, 3, 4, 5, 6, 7);
        }
#pragma unroll
        for (int ct = 0; ct < 2; ++ct) {
            const size_t woff = (size_t)(cq + ct * 16 + l15) * IN_DIM + k0 + quad * 8;
            bf16x8 wh = *(const bf16x8*)(Wb_h + woff);
            bf16x8 wl = *(const bf16x8*)(Wb_l + woff);
            acc[0][ct] = __builtin_amdgcn_mfma_f32_16x16x32_bf16(ah[0], wh, acc[0][ct], 0, 0, 0);
            acc[1][ct] = __builtin_amdgcn_mfma_f32_16x16x32_bf16(ah[1], wh, acc[1][ct], 0, 0, 0);
            acc[0][ct] = __builtin_amdgcn_mfma_f32_16x16x32_bf16(al[0], wh, acc[0][ct], 0, 0, 0);
            acc[1][ct] = __builtin_amdgcn_mfma_f32_16x16x32_bf16(al[1], wh, acc[1][ct], 0, 0, 0);
            acc[0][ct] = __builtin_amdgcn_mfma_f32_16x16x32_bf16(ah[0], wl, acc[0][ct], 0, 0, 0);
            acc[1][ct] = __builtin_amdgcn_mfma_f32_16x16x32_bf16(ah[1], wl, acc[1][ct], 0, 0, 0);
        }
    }

    // ---- epilogue 2: out = relu(acc + bb) -> global ----
#pragma unroll
    for (int ti = 0; ti < 2; ++ti) {
        const int rbase = brow + rh + ti * 16 + quad * 4;
#pragma unroll
        for (int ct = 0; ct < 2; ++ct) {
            int col = cq + ct * 16 + l15;
            float b = bb[col];
#pragma unroll
            for (int r = 0; r < 4; ++r) {
                int row = rbase + r;
                if (row < M) {
                    float o = fmaxf(acc[ti][ct][r] + b, 0.f);
                    if constexpr (LAYER == 1) {
                        unsigned short hh = bf16_rne(o);
                        Ch[(size_t)row * IN_DIM + col] = hh;
                        Cl[(size_t)row * IN_DIM + col] =
                            bf16_rne(o - __uint_as_float(((unsigned)hh) << 16));
                    } else {
                        C[(size_t)row * IN_DIM + col] = o;
                    }
                }
            }
        }
    }
}

// ---------------- pool + heads ---------------------------------------------

__device__ __forceinline__ int lower_bound_i(const int* __restrict__ a, int n, int v) {
    int lo = 0, hi = n;
    while (lo < hi) {
        int mid = (lo + hi) >> 1;
        if (a[mid] < v) lo = mid + 1; else hi = mid;
    }
    return lo;
}

__global__ __launch_bounds__(128) void pool_kernel(
    const float* __restrict__ h, const int* __restrict__ batch,
    float* __restrict__ pooled, int n_nodes, int n_graphs)
{
    int g = blockIdx.x;
    int lo = lower_bound_i(batch, n_nodes, g);
    int hi = lower_bound_i(batch, n_nodes, g + 1);
    int j = threadIdx.x;
    float acc = 0.f;
    for (int i = lo; i < hi; ++i)
        acc += h[(size_t)i * IN_DIM + j];
    float cnt = (float)(hi - lo);
    pooled[(size_t)g * IN_DIM + j] = acc / fmaxf(cnt, 1.0f);
}

__global__ __launch_bounds__(64) void head_kernel(
    const float* __restrict__ pooled,
    const float* __restrict__ Ws,  const float* __restrict__ bs,
    const float* __restrict__ WlS, const float* __restrict__ blS,
    const float* __restrict__ WlP, const float* __restrict__ blP,
    const float* __restrict__ WnR, const float* __restrict__ bnR,
    float* __restrict__ out, int n_graphs)
{
    int g = blockIdx.x;
    int j = threadIdx.x;
    const float* p = pooled + (size_t)g * IN_DIM;
    float acc = bs[j];
#pragma unroll 8
    for (int k = 0; k < IN_DIM; ++k)
        acc = fmaf(p[k], Ws[k * 64 + j], acc);
    float gj = fmaxf(acc, 0.f);
    float s1 = gj * WlS[j];
    float s2 = gj * WlP[j];
    float s3 = gj * WnR[j];
#pragma unroll
    for (int off = 32; off > 0; off >>= 1) {
        s1 += __shfl_down(s1, off);
        s2 += __shfl_down(s2, off);
        s3 += __shfl_down(s3, off);
    }
    if (j == 0) {
        out[g]                = s1 + blS[0];
        out[n_graphs + g]     = s2 + blP[0];
        out[2 * n_graphs + g] = s3 + bnR[0];
    }
}

// ---------------- launch ---------------------------------------------------

extern "C" void kernel_launch(void* const* d_in, const int* in_sizes, int n_in,
                              void* d_out, int out_size, void* d_ws, size_t ws_size,
                              hipStream_t stream)
{
    const float* x   = (const float*)d_in[0];
    const int*   ei  = (const int*)d_in[1];
    const int*   bat = (const int*)d_in[2];
    const float* W1a = (const float*)d_in[3];
    const float* b1a = (const float*)d_in[4];
    const float* W1b = (const float*)d_in[5];
    const float* b1b = (const float*)d_in[6];
    const float* W2a = (const float*)d_in[7];
    const float* b2a = (const float*)d_in[8];
    const float* W2b = (const float*)d_in[9];
    const float* b2b = (const float*)d_in[10];
    const float* Ws  = (const float*)d_in[11];
    const float* bs  = (const float*)d_in[12];
    const float* WlS = (const float*)d_in[13];
    const float* blS = (const float*)d_in[14];
    const float* WlP = (const float*)d_in[15];
    const float* blP = (const float*)d_in[16];
    const float* WnR = (const float*)d_in[17];
    const float* bnR = (const float*)d_in[18];

    const int n_nodes  = in_sizes[0] / IN_DIM;
    const int n_edges  = in_sizes[1] / 2;
    const int n_graphs = out_size / 3;
    const int* src = ei;
    const int* dst = ei + n_edges;

    const size_t node_elems   = (size_t)n_nodes * IN_DIM;
    const size_t pooled_elems = (size_t)n_graphs * IN_DIM;

    // ws layout:
    //   xb : bf16 of x            (node_elems ushort)
    //   Ch : layer-1 out high     (node_elems ushort)
    //   Cl : layer-1 out low      (node_elems ushort)
    //   P3 : layer-2 out fp32     (node_elems float)    [buckets alias here]
    //   pooled, row_start, bcur, csr_src, wt planes, rcs
    unsigned short* xb = (unsigned short*)d_ws;
    unsigned short* Ch = xb + node_elems;
    unsigned short* Cl = Ch + node_elems;
    float* P3     = (float*)(Cl + node_elems);
    float* pooled = P3 + node_elems;
    int* row_start = (int*)(pooled + pooled_elems);   // n_nodes + 1
    int* bcur      = row_start + (n_nodes + 1);       // NFINE bucket cursors
    int* csr_src   = bcur + NFINE;                    // n_edges
    unsigned short* wt_h = (unsigned short*)(csr_src + n_edges);  // 4 * 16384
    unsigned short* wt_l = wt_h + 4 * 16384;
    int* rcs       = (int*)(wt_l + 4 * 16384);        // n_nodes * SRCCH

    const int cap = n_edges / NFINE + 2048;           // ~18 sigma slack
    int2* buckets = (int2*)P3;                        // 128*cap*8B ~= 15MB

    const int layerblocks = (n_nodes + 63) / 64;
    const int binblocks = (n_edges + BIN_EPB - 1) / BIN_EPB;
    const int n8 = (int)(node_elems / 8);
    const int cvtblocks = (n8 + 255) / 256;

    // ---- weight conversion + CSR build ----
    conv_weights_kernel<<<256, 256, 0, stream>>>(W1a, W1b, W2a, W2b, wt_h, wt_l);
    hipMemsetAsync(bcur, 0, NFINE * sizeof(int), stream);
    bin_kernel<<<binblocks, 256, 0, stream>>>(src, dst, buckets, bcur,
                                              n_edges, n_nodes, cap);
    csr_fused_kernel<<<NFINE, 512, 0, stream>>>(buckets, bcur, row_start, rcs,
                                                csr_src, cap, n_nodes, n_edges);
    f32_to_bf16_kernel<<<cvtblocks, 256, 0, stream>>>((const float4*)x, (uint4*)xb, n8);

    // ---- layer 1 (fused gather + MLP) ----
    fused_gin_layer_kernel<1><<<layerblocks, 512, 0, stream>>>(
        x, nullptr, nullptr, (const uint4*)xb, row_start, rcs, csr_src,
        wt_h, wt_l, b1a, wt_h + 16384, wt_l + 16384, b1b,
        nullptr, Ch, Cl, n_nodes);

    // ---- layer 2 (fused gather + MLP) ----
    fused_gin_layer_kernel<2><<<layerblocks, 512, 0, stream>>>(
        nullptr, (const uint4*)Ch, (const uint4*)Cl, (const uint4*)Ch,
        row_start, rcs, csr_src,
        wt_h + 2 * 16384, wt_l + 2 * 16384, b2a,
        wt_h + 3 * 16384, wt_l + 3 * 16384, b2b,
        P3, nullptr, nullptr, n_nodes);

    // ---- pool + heads ----
    pool_kernel<<<n_graphs, 128, 0, stream>>>(P3, bat, pooled, n_nodes, n_graphs);
    head_kernel<<<n_graphs, 64, 0, stream>>>(pooled, Ws, bs, WlS, blS, WlP, blP,
                                             WnR, bnR, (float*)d_out, n_graphs);
}

// Round 5
// 319.853 us; speedup vs baseline: 1.1608x; 1.1608x over previous
//
#include <hip/hip_runtime.h>
#include <hip/hip_bf16.h>

// ---------------------------------------------------------------------------
// GIN multi-task forward on MI355X.
// R22: layer kernel reverted to R19 exactly (proven 80.7us; R20/R21 both
// regressed it -- R19 sits at the compulsory-fetch x ~2TB/s random-miss
// ceiling: FETCH 134MB = 12.8MB nbr table x 8 XCDs + self 25.6 + csr 6.4).
// This round attacks the ~183us OUTSIDE the layers:
//  (a) NFINE 128->256: csr_fused was 128 blocks = half GPU idle.
//  (b) setup_kernel merges weight-split + x->bf16 + bcur/pooled zeroing
//      (10 dispatches -> 6, fewer launch gaps).
//  (c) pool fused into layer-2 epilogue: 64x128 tile staged in LDS,
//      per-column segment-reduce over sorted batch ids, ~384 atomicAdds
//      per block into pooled. Deletes pool_kernel + 25.6MB C write.
//      head_kernel divides by count (binary search).
// ---------------------------------------------------------------------------

#define IN_DIM 128
#define NFINE 256        // fine dst buckets (32 per XCD)
#define BIN_EPB 4096     // edges per bin block (16/thread)
#define SRCCH 16         // src chunks per dst row (sorted order)
#define NSLOT 3200       // >= ceil(50000/256)*16 = 3136
#define SPT 7            // scan slots per thread (512*7 >= 3200)

typedef float  f32x4  __attribute__((ext_vector_type(4)));
typedef short  bf16x4 __attribute__((ext_vector_type(4)));
typedef short  bf16x8 __attribute__((ext_vector_type(8)));

__device__ __forceinline__ unsigned short bf16_rne(float v) {
    unsigned u = __float_as_uint(v);
    unsigned t = u + 0x7fffu + ((u >> 16) & 1u);
    return (unsigned short)(t >> 16);
}

// ---------------- setup: x->bf16, weight split, zero bcur/pooled -----------

__global__ __launch_bounds__(256) void setup_kernel(
    const float4* __restrict__ xin, uint4* __restrict__ xb, int n8,
    const float* __restrict__ W0, const float* __restrict__ W1,
    const float* __restrict__ W2, const float* __restrict__ W3,
    unsigned short* __restrict__ Wh, unsigned short* __restrict__ Wl,
    int* __restrict__ bcur, float* __restrict__ pooled, int npool)
{
    int gid = blockIdx.x * 256 + threadIdx.x;
    if (gid < n8) {
        float4 a = xin[gid * 2];
        float4 b = xin[gid * 2 + 1];
        float v[8] = {a.x, a.y, a.z, a.w, b.x, b.y, b.z, b.w};
        unsigned r[4];
#pragma unroll
        for (int j = 0; j < 4; ++j)
            r[j] = (unsigned)bf16_rne(v[j * 2]) | ((unsigned)bf16_rne(v[j * 2 + 1]) << 16);
        xb[gid] = make_uint4(r[0], r[1], r[2], r[3]);
    }
    if (gid < 4 * 16384) {
        int m   = gid >> 14;
        int idx = gid & 16383;
        const float* W = (m == 0) ? W0 : (m == 1) ? W1 : (m == 2) ? W2 : W3;
        int k = idx >> 7, n = idx & 127;
        float v = W[idx];
        unsigned short hh = bf16_rne(v);
        float hf = __uint_as_float(((unsigned)hh) << 16);
        unsigned short ll = bf16_rne(v - hf);
        Wh[m * 16384 + n * 128 + k] = hh;
        Wl[m * 16384 + n * 128 + k] = ll;
    }
    if (gid < NFINE) bcur[gid] = 0;
    if (gid < npool) pooled[gid] = 0.f;
}

// ---------------- CSR build: 256-way bin -> fused hist/scan/fill -----------

__global__ __launch_bounds__(256) void bin_kernel(
    const int* __restrict__ src, const int* __restrict__ dst,
    int2* __restrict__ buckets, int* __restrict__ bcur,
    int n_edges, int n_nodes, int cap)
{
    __shared__ int cnt[NFINE];
    __shared__ int base[NFINE];
    for (int i = threadIdx.x; i < NFINE; i += 256) cnt[i] = 0;
    __syncthreads();

    const int e0 = blockIdx.x * BIN_EPB + threadIdx.x * 16;
    int ne = n_edges - e0;
    if (ne < 0) ne = 0;
    if (ne > 16) ne = 16;

    int d[16], s[16], off[16];
    if (ne == 16) {
#pragma unroll
        for (int q = 0; q < 4; ++q) {
            int4 dv = *(const int4*)(dst + e0 + q * 4);
            int4 sv = *(const int4*)(src + e0 + q * 4);
            d[q * 4 + 0] = dv.x; d[q * 4 + 1] = dv.y;
            d[q * 4 + 2] = dv.z; d[q * 4 + 3] = dv.w;
            s[q * 4 + 0] = sv.x; s[q * 4 + 1] = sv.y;
            s[q * 4 + 2] = sv.z; s[q * 4 + 3] = sv.w;
        }
    } else {
#pragma unroll
        for (int j = 0; j < 16; ++j) {
            d[j] = (j < ne) ? dst[e0 + j] : 0;
            s[j] = (j < ne) ? src[e0 + j] : 0;
        }
    }
#pragma unroll
    for (int j = 0; j < 16; ++j)
        if (j < ne) {
            int b = (int)(((long long)d[j] * NFINE) / n_nodes);
            off[j] = atomicAdd(&cnt[b], 1);
        }
    __syncthreads();
    for (int i = threadIdx.x; i < NFINE; i += 256)
        base[i] = atomicAdd(&bcur[i], cnt[i]);
    __syncthreads();
#pragma unroll
    for (int j = 0; j < 16; ++j)
        if (j < ne) {
            int b = (int)(((long long)d[j] * NFINE) / n_nodes);
            buckets[(size_t)b * cap + base[b] + off[j]] = make_int2(d[j], s[j]);
        }
}

// One block per fine bucket. Per-(node, src-chunk16) LDS histogram, blocked
// exclusive scan (SPT slots/thread), row_start write, LDS-cursor fill ->
// csr rows stored sorted by src chunk (gather L2 locality).
__global__ __launch_bounds__(512) void csr_fused_kernel(
    const int2* __restrict__ buckets, const int* __restrict__ bcnt,
    int* __restrict__ row_start, int* __restrict__ csr_src,
    int cap, int n_nodes, int n_edges)
{
    __shared__ int bc[NFINE];
    __shared__ int h[NSLOT];
    __shared__ int tsum[512];
    __shared__ int bbase_s;

    const int b = blockIdx.x;
    const int t = threadIdx.x;
    const int lo_n = (int)(((long long)b * n_nodes + NFINE - 1) / NFINE);
    const int hi_n = (int)(((long long)(b + 1) * n_nodes + NFINE - 1) / NFINE);
    const int sl = hi_n - lo_n;

    for (int i = t; i < NFINE; i += 512) bc[i] = bcnt[i];
    for (int i = t; i < NSLOT; i += 512) h[i] = 0;
    __syncthreads();
    if (t == 0) {
        int s = 0;
        for (int i = 0; i < b; ++i) s += bc[i];
        bbase_s = s;
    }
    const int nb = bc[b];
    const int2* bp = buckets + (size_t)b * cap;
    __syncthreads();

    // pass 1: per-(node, src-chunk) histogram
    for (int i = t; i < nb; i += 512) {
        int2 e = bp[i];
        int key = (e.x - lo_n) * SRCCH + (int)(((long long)e.y * SRCCH) / n_nodes);
        atomicAdd(&h[key], 1);
    }
    __syncthreads();

    // blocked exclusive scan over NSLOT entries (SPT per thread)
    int base = 0;
#pragma unroll
    for (int j = 0; j < SPT; ++j) {
        int slot = t * SPT + j;
        if (slot < NSLOT) {
            int v = h[slot];
            h[slot] = base;
            base += v;
        }
    }
    tsum[t] = base;
    __syncthreads();
    for (int off = 1; off < 512; off <<= 1) {
        int tmp = (t >= off) ? tsum[t - off] : 0;
        __syncthreads();
        tsum[t] += tmp;
        __syncthreads();
    }
    int texcl = tsum[t] - base + bbase_s;
#pragma unroll
    for (int j = 0; j < SPT; ++j) {
        int slot = t * SPT + j;
        if (slot < NSLOT) h[slot] += texcl;
    }
    __syncthreads();
    for (int i = t; i < sl; i += 512) row_start[lo_n + i] = h[i * SRCCH];
    if (b == NFINE - 1 && t == 0) row_start[n_nodes] = n_edges;
    __syncthreads();

    // pass 2: fill with LDS cursors (exclusive csr window, full-line writes)
    for (int i = t; i < nb; i += 512) {
        int2 e = bp[i];
        int key = (e.x - lo_n) * SRCCH + (int)(((long long)e.y * SRCCH) / n_nodes);
        csr_src[atomicAdd(&h[key], 1)] = e.y;
    }
}

// ---------------- fused layer: gather + relu(relu(A@Wa+ba)@Wb+bb) ----------
// Block = 512 thr (8 waves) = 64 nodes. Phase G = R19 gather (4-deep loop).
// Phase 1: A(LDS)@Wa; epilogue-1 overwrites LDS with split-bf16 H.
// Phase 2: H(LDS)@Wb. Epilogue-2: LAYER1 -> split-bf16 Ch/Cl to global;
// LAYER2 -> stage fp32 tile in LDS, per-column segment-reduce over sorted
// batch ids, atomicAdd partials into pooled (pool fusion).
#define HSTRIDE 132

__device__ __forceinline__ void add_row8(float acc[8], uint4 r) {
    union { unsigned u; float f; } c;
    c.u = r.x << 16;         acc[0] += c.f;
    c.u = r.x & 0xffff0000u; acc[1] += c.f;
    c.u = r.y << 16;         acc[2] += c.f;
    c.u = r.y & 0xffff0000u; acc[3] += c.f;
    c.u = r.z << 16;         acc[4] += c.f;
    c.u = r.z & 0xffff0000u; acc[5] += c.f;
    c.u = r.w << 16;         acc[6] += c.f;
    c.u = r.w & 0xffff0000u; acc[7] += c.f;
}

template <int LAYER>
__global__ __launch_bounds__(512) void fused_gin_layer_kernel(
    const float* __restrict__ xf,        // layer-1 self rows (fp32)
    const uint4* __restrict__ selfh,     // layer-2 self high plane
    const uint4* __restrict__ selfl,     // layer-2 self low plane
    const uint4* __restrict__ nbr,       // neighbor bf16 rows, 16 uint4/row
    const int* __restrict__ row_start, const int* __restrict__ csr_src,
    const unsigned short* __restrict__ Wa_h, const unsigned short* __restrict__ Wa_l,
    const float* __restrict__ ba,
    const unsigned short* __restrict__ Wb_h, const unsigned short* __restrict__ Wb_l,
    const float* __restrict__ bb,
    unsigned short* __restrict__ Ch, unsigned short* __restrict__ Cl,
    float* __restrict__ pooled, const int* __restrict__ batch, int M)
{
    __shared__ __align__(16) unsigned short LDSBUF[2][64][HSTRIDE];
    __shared__ int sbatch[64];
    auto& Hh = LDSBUF[0];
    auto& Hl = LDSBUF[1];

    const int t    = threadIdx.x;
    const int brow = blockIdx.x * 64;

    // ---- phase G: gather 64 nodes -> split-bf16 A planes in LDS ----
    {
        const int lane = t & 15;         // k-slice: elems [lane*8, lane*8+8)
        const int gr   = t >> 4;         // 0..31
#pragma unroll
        for (int it = 0; it < 2; ++it) {
            const int rl   = it * 32 + gr;
            const int node = brow + rl;
            float acc[8] = {0.f, 0.f, 0.f, 0.f, 0.f, 0.f, 0.f, 0.f};
            if (node < M) {
                if constexpr (LAYER == 1) {
                    const f32x4* xfr = (const f32x4*)(xf + (size_t)node * IN_DIM + lane * 8);
                    f32x4 a0 = xfr[0];
                    f32x4 a1 = xfr[1];
                    acc[0] = a0.x; acc[1] = a0.y; acc[2] = a0.z; acc[3] = a0.w;
                    acc[4] = a1.x; acc[5] = a1.y; acc[6] = a1.z; acc[7] = a1.w;
                } else {
                    add_row8(acc, selfh[(size_t)node * 16 + lane]);
                    add_row8(acc, selfl[(size_t)node * 16 + lane]);
                }
                const int lo = row_start[node];
                const int hi = row_start[node + 1];
                int e = lo;
                for (; e + 3 < hi; e += 4) {
                    int s0 = csr_src[e];
                    int s1 = csr_src[e + 1];
                    int s2 = csr_src[e + 2];
                    int s3 = csr_src[e + 3];
                    uint4 r0 = nbr[(size_t)s0 * 16 + lane];
                    uint4 r1 = nbr[(size_t)s1 * 16 + lane];
                    uint4 r2 = nbr[(size_t)s2 * 16 + lane];
                    uint4 r3 = nbr[(size_t)s3 * 16 + lane];
                    add_row8(acc, r0);
                    add_row8(acc, r1);
                    add_row8(acc, r2);
                    add_row8(acc, r3);
                }
                for (; e < hi; ++e)
                    add_row8(acc, nbr[(size_t)csr_src[e] * 16 + lane]);
            }
            unsigned short hh[8], ll[8];
#pragma unroll
            for (int j = 0; j < 8; ++j) {
                unsigned short h = bf16_rne(acc[j]);
                hh[j] = h;
                ll[j] = bf16_rne(acc[j] - __uint_as_float(((unsigned)h) << 16));
            }
            *(bf16x4*)&Hh[rl][lane * 8]     = *(const bf16x4*)&hh[0];
            *(bf16x4*)&Hh[rl][lane * 8 + 4] = *(const bf16x4*)&hh[4];
            *(bf16x4*)&Hl[rl][lane * 8]     = *(const bf16x4*)&ll[0];
            *(bf16x4*)&Hl[rl][lane * 8 + 4] = *(const bf16x4*)&ll[4];
        }
    }
    __syncthreads();

    // ---- MLP thread decomposition: wave owns 32x32 quadrant ----
    const int wave = t >> 6;
    const int lane = t & 63;
    const int l15  = lane & 15;
    const int quad = lane >> 4;
    const int rh   = (wave & 1) * 32;        // row half within block
    const int cq   = (wave >> 1) * 32;       // col quarter

    f32x4 acc[2][2];
#pragma unroll
    for (int ti = 0; ti < 2; ++ti)
#pragma unroll
        for (int ct = 0; ct < 2; ++ct) acc[ti][ct] = {0.f, 0.f, 0.f, 0.f};

    // ---- phase 1: A (LDS, split bf16) @ Wa ----
#pragma unroll
    for (int k0 = 0; k0 < IN_DIM; k0 += 32) {
        const int hk = k0 + quad * 8;
        bf16x8 ah[2], al[2];
#pragma unroll
        for (int ti = 0; ti < 2; ++ti) {
            const int hr = rh + ti * 16 + l15;
            bf16x4 h0 = *(const bf16x4*)&Hh[hr][hk];
            bf16x4 h1 = *(const bf16x4*)&Hh[hr][hk + 4];
            bf16x4 l0 = *(const bf16x4*)&Hl[hr][hk];
            bf16x4 l1 = *(const bf16x4*)&Hl[hr][hk + 4];
            ah[ti] = __builtin_shufflevector(h0, h1, 0, 1, 2, 3, 4, 5, 6, 7);
            al[ti] = __builtin_shufflevector(l0, l1, 0, 1, 2, 3, 4, 5, 6, 7);
        }
#pragma unroll
        for (int ct = 0; ct < 2; ++ct) {
            const size_t woff = (size_t)(cq + ct * 16 + l15) * IN_DIM + k0 + quad * 8;
            bf16x8 wh = *(const bf16x8*)(Wa_h + woff);
            bf16x8 wl = *(const bf16x8*)(Wa_l + woff);
            acc[0][ct] = __builtin_amdgcn_mfma_f32_16x16x32_bf16(ah[0], wh, acc[0][ct], 0, 0, 0);
            acc[1][ct] = __builtin_amdgcn_mfma_f32_16x16x32_bf16(ah[1], wh, acc[1][ct], 0, 0, 0);
            acc[0][ct] = __builtin_amdgcn_mfma_f32_16x16x32_bf16(al[0], wh, acc[0][ct], 0, 0, 0);
            acc[1][ct] = __builtin_amdgcn_mfma_f32_16x16x32_bf16(al[1], wh, acc[1][ct], 0, 0, 0);
            acc[0][ct] = __builtin_amdgcn_mfma_f32_16x16x32_bf16(ah[0], wl, acc[0][ct], 0, 0, 0);
            acc[1][ct] = __builtin_amdgcn_mfma_f32_16x16x32_bf16(ah[1], wl, acc[1][ct], 0, 0, 0);
        }
    }
    __syncthreads();   // all stage-1 LDS reads done before H overwrite

    // ---- epilogue 1: h = relu(acc + ba) -> LDS (overwrite A planes) ----
#pragma unroll
    for (int ti = 0; ti < 2; ++ti) {
#pragma unroll
        for (int ct = 0; ct < 2; ++ct) {
            int col = cq + ct * 16 + l15;
            float b = ba[col];
#pragma unroll
            for (int r = 0; r < 4; ++r) {
                int rl = rh + ti * 16 + quad * 4 + r;
                float v = fmaxf(acc[ti][ct][r] + b, 0.f);
                unsigned short hh = bf16_rne(v);
                Hh[rl][col] = hh;
                Hl[rl][col] = bf16_rne(v - __uint_as_float(((unsigned)hh) << 16));
            }
            acc[ti][ct] = {0.f, 0.f, 0.f, 0.f};
        }
    }
    __syncthreads();

    // ---- phase 2: h (LDS, split bf16) @ Wb ----
#pragma unroll
    for (int k0 = 0; k0 < IN_DIM; k0 += 32) {
        const int hk = k0 + quad * 8;
        bf16x8 ah[2], al[2];
#pragma unroll
        for (int ti = 0; ti < 2; ++ti) {
            const int hr = rh + ti * 16 + l15;
            bf16x4 h0 = *(const bf16x4*)&Hh[hr][hk];
            bf16x4 h1 = *(const bf16x4*)&Hh[hr][hk + 4];
            bf16x4 l0 = *(const bf16x4*)&Hl[hr][hk];
            bf16x4 l1 = *(const bf16x4*)&Hl[hr][hk + 4];
            ah[ti] = __builtin_shufflevector(h0, h1, 0, 1, 2, 3, 4, 5, 6, 7);
            al[ti] = __builtin_shufflevector(l0, l1, 0, 1, 2, 3, 4, 5, 6, 7);
        }
#pragma unroll
        for (int ct = 0; ct < 2; ++ct) {
            const size_t woff = (size_t)(cq + ct * 16 + l15) * IN_DIM + k0 + quad * 8;
            bf16x8 wh = *(const bf16x8*)(Wb_h + woff);
            bf16x8 wl = *(const bf16x8*)(Wb_l + woff);
            acc[0][ct] = __builtin_amdgcn_mfma_f32_16x16x32_bf16(ah[0], wh, acc[0][ct], 0, 0, 0);
            acc[1][ct] = __builtin_amdgcn_mfma_f32_16x16x32_bf16(ah[1], wh, acc[1][ct], 0, 0, 0);
            acc[0][ct] = __builtin_amdgcn_mfma_f32_16x16x32_bf16(al[0], wh, acc[0][ct], 0, 0, 0);
            acc[1][ct] = __builtin_amdgcn_mfma_f32_16x16x32_bf16(al[1], wh, acc[1][ct], 0, 0, 0);
            acc[0][ct] = __builtin_amdgcn_mfma_f32_16x16x32_bf16(ah[0], wl, acc[0][ct], 0, 0, 0);
            acc[1][ct] = __builtin_amdgcn_mfma_f32_16x16x32_bf16(ah[1], wl, acc[1][ct], 0, 0, 0);
        }
    }

    // ---- epilogue 2 ----
    if constexpr (LAYER == 1) {
        // split-bf16 Ch/Cl to global (layer-2 input)
#pragma unroll
        for (int ti = 0; ti < 2; ++ti) {
            const int rbase = brow + rh + ti * 16 + quad * 4;
#pragma unroll
            for (int ct = 0; ct < 2; ++ct) {
                int col = cq + ct * 16 + l15;
                float b = bb[col];
#pragma unroll
                for (int r = 0; r < 4; ++r) {
                    int row = rbase + r;
                    if (row < M) {
                        float o = fmaxf(acc[ti][ct][r] + b, 0.f);
                        unsigned short hh = bf16_rne(o);
                        Ch[(size_t)row * IN_DIM + col] = hh;
                        Cl[(size_t)row * IN_DIM + col] =
                            bf16_rne(o - __uint_as_float(((unsigned)hh) << 16));
                    }
                }
            }
        }
    } else {
        // fused mean-pool: stage fp32 tile in LDS, segment-reduce per column
        __syncthreads();   // phase-2 LDS reads complete before overwrite
        float* ftile = (float*)&LDSBUF[0][0][0];   // 64*128*4B = 32KB <= 33.8KB
#pragma unroll
        for (int ti = 0; ti < 2; ++ti) {
#pragma unroll
            for (int ct = 0; ct < 2; ++ct) {
                int col = cq + ct * 16 + l15;
                float b = bb[col];
#pragma unroll
                for (int r = 0; r < 4; ++r) {
                    int rl = rh + ti * 16 + quad * 4 + r;
                    ftile[rl * 128 + col] = fmaxf(acc[ti][ct][r] + b, 0.f);
                }
            }
        }
        if (t < 64) {
            int node = brow + t;
            sbatch[t] = (node < M) ? batch[node] : -1;
        }
        __syncthreads();
        if (t < 128) {
            const int col = t;
            float run = 0.f;
            int curg = sbatch[0];
#pragma unroll 1
            for (int r = 0; r < 64; ++r) {
                int g = sbatch[r];
                if (g != curg) {
                    if (curg >= 0)
                        atomicAdd(&pooled[(size_t)curg * IN_DIM + col], run);
                    curg = g;
                    run = 0.f;
                }
                if (g >= 0) run += ftile[r * 128 + col];
            }
            if (curg >= 0)
                atomicAdd(&pooled[(size_t)curg * IN_DIM + col], run);
        }
    }
}

// ---------------- heads (mean divide folded in) ----------------------------

__device__ __forceinline__ int lower_bound_i(const int* __restrict__ a, int n, int v) {
    int lo = 0, hi = n;
    while (lo < hi) {
        int mid = (lo + hi) >> 1;
        if (a[mid] < v) lo = mid + 1; else hi = mid;
    }
    return lo;
}

__global__ __launch_bounds__(64) void head_kernel(
    const float* __restrict__ pooled, const int* __restrict__ batch, int n_nodes,
    const float* __restrict__ Ws,  const float* __restrict__ bs,
    const float* __restrict__ WlS, const float* __restrict__ blS,
    const float* __restrict__ WlP, const float* __restrict__ blP,
    const float* __restrict__ WnR, const float* __restrict__ bnR,
    float* __restrict__ out, int n_graphs)
{
    int g = blockIdx.x;
    int j = threadIdx.x;
    int lo = lower_bound_i(batch, n_nodes, g);
    int hi = lower_bound_i(batch, n_nodes, g + 1);
    float inv = 1.f / fmaxf((float)(hi - lo), 1.0f);
    const float* p = pooled + (size_t)g * IN_DIM;
    float acc = 0.f;
#pragma unroll 8
    for (int k = 0; k < IN_DIM; ++k)
        acc = fmaf(p[k], Ws[k * 64 + j], acc);
    float gj = fmaxf(acc * inv + bs[j], 0.f);
    float s1 = gj * WlS[j];
    float s2 = gj * WlP[j];
    float s3 = gj * WnR[j];
#pragma unroll
    for (int off = 32; off > 0; off >>= 1) {
        s1 += __shfl_down(s1, off);
        s2 += __shfl_down(s2, off);
        s3 += __shfl_down(s3, off);
    }
    if (j == 0) {
        out[g]                = s1 + blS[0];
        out[n_graphs + g]     = s2 + blP[0];
        out[2 * n_graphs + g] = s3 + bnR[0];
    }
}

// ---------------- launch ---------------------------------------------------

extern "C" void kernel_launch(void* const* d_in, const int* in_sizes, int n_in,
                              void* d_out, int out_size, void* d_ws, size_t ws_size,
                              hipStream_t stream)
{
    const float* x   = (const float*)d_in[0];
    const int*   ei  = (const int*)d_in[1];
    const int*   bat = (const int*)d_in[2];
    const float* W1a = (const float*)d_in[3];
    const float* b1a = (const float*)d_in[4];
    const float* W1b = (const float*)d_in[5];
    const float* b1b = (const float*)d_in[6];
    const float* W2a = (const float*)d_in[7];
    const float* b2a = (const float*)d_in[8];
    const float* W2b = (const float*)d_in[9];
    const float* b2b = (const float*)d_in[10];
    const float* Ws  = (const float*)d_in[11];
    const float* bs  = (const float*)d_in[12];
    const float* WlS = (const float*)d_in[13];
    const float* blS = (const float*)d_in[14];
    const float* WlP = (const float*)d_in[15];
    const float* blP = (const float*)d_in[16];
    const float* WnR = (const float*)d_in[17];
    const float* bnR = (const float*)d_in[18];

    const int n_nodes  = in_sizes[0] / IN_DIM;
    const int n_edges  = in_sizes[1] / 2;
    const int n_graphs = out_size / 3;
    const int* src = ei;
    const int* dst = ei + n_edges;

    const size_t node_elems   = (size_t)n_nodes * IN_DIM;
    const size_t pooled_elems = (size_t)n_graphs * IN_DIM;

    // ws layout:
    //   xb : bf16 of x            (node_elems ushort)
    //   Ch : layer-1 out high     (node_elems ushort)   [buckets alias Ch+Cl]
    //   Cl : layer-1 out low      (node_elems ushort)
    //   pooled (n_graphs*128 f32), row_start, bcur, csr_src, wt planes
    unsigned short* xb = (unsigned short*)d_ws;
    unsigned short* Ch = xb + node_elems;
    unsigned short* Cl = Ch + node_elems;
    float* pooled = (float*)(Cl + node_elems);
    int* row_start = (int*)(pooled + pooled_elems);   // n_nodes + 1
    int* bcur      = row_start + (n_nodes + 1);       // NFINE bucket cursors
    int* csr_src   = bcur + NFINE;                    // n_edges
    unsigned short* wt_h = (unsigned short*)(csr_src + n_edges);  // 4 * 16384
    unsigned short* wt_l = wt_h + 4 * 16384;

    const int cap = n_edges / NFINE + 2048;           // mean 6250 + ~25 sigma
    int2* buckets = (int2*)Ch;                        // 256*cap*8B ~= 17MB, dead after csr

    const int layerblocks = (n_nodes + 63) / 64;
    const int binblocks = (n_edges + BIN_EPB - 1) / BIN_EPB;
    const int n8 = (int)(node_elems / 8);
    const int cvtblocks = (n8 + 255) / 256;

    // ---- setup (x cvt + weight split + zero bcur/pooled) + CSR build ----
    setup_kernel<<<cvtblocks, 256, 0, stream>>>(
        (const float4*)x, (uint4*)xb, n8, W1a, W1b, W2a, W2b,
        wt_h, wt_l, bcur, pooled, (int)pooled_elems);
    bin_kernel<<<binblocks, 256, 0, stream>>>(src, dst, buckets, bcur,
                                              n_edges, n_nodes, cap);
    csr_fused_kernel<<<NFINE, 512, 0, stream>>>(buckets, bcur, row_start,
                                                csr_src, cap, n_nodes, n_edges);

    // ---- layer 1 (fused gather + MLP) ----
    fused_gin_layer_kernel<1><<<layerblocks, 512, 0, stream>>>(
        x, nullptr, nullptr, (const uint4*)xb, row_start, csr_src,
        wt_h, wt_l, b1a, wt_h + 16384, wt_l + 16384, b1b,
        Ch, Cl, nullptr, nullptr, n_nodes);

    // ---- layer 2 (fused gather + MLP + mean-pool) ----
    fused_gin_layer_kernel<2><<<layerblocks, 512, 0, stream>>>(
        nullptr, (const uint4*)Ch, (const uint4*)Cl, (const uint4*)Ch,
        row_start, csr_src,
        wt_h + 2 * 16384, wt_l + 2 * 16384, b2a,
        wt_h + 3 * 16384, wt_l + 3 * 16384, b2b,
        nullptr, nullptr, pooled, bat, n_nodes);

    // ---- heads ----
    head_kernel<<<n_graphs, 64, 0, stream>>>(pooled, bat, n_nodes,
                                             Ws, bs, WlS, blS, WlP, blP,
                                             WnR, bnR, (float*)d_out, n_graphs);
}